// Round 1
// baseline (1205.001 us; speedup 1.0000x reference)
//
#include <hip/hip_runtime.h>
#include <cfloat>
#include <cmath>

// Problem constants (from reference): x (N,T,D) fp32, lengths (N,) int, w (D,) fp32
constexpr int N = 32;
constexpr int T = 4000;
constexpr int D = 2048;
constexpr int R = 10;

// 16 rows per block (4 waves x 4 rows), 250 blocks per n covers T=4000 exactly.
constexpr int ROWS_PER_BLOCK = 16;
constexpr int BLOCKS_PER_N = T / ROWS_PER_BLOCK; // 250

// Phase 1: scores[n,t] = dot(x[n,t,:], w) for t < lengths[n].
// One wave per row. Lane i handles float4 indices {i, i+64, ..., i+448} of the
// 512-float4 row; w fragment for those indices is preloaded into registers once.
__global__ __launch_bounds__(256) void score_kernel(
    const float* __restrict__ x, const int* __restrict__ lengths,
    const float* __restrict__ w, float* __restrict__ scores) {
  const int n = blockIdx.x / BLOCKS_PER_N;
  const int tbase = (blockIdx.x % BLOCKS_PER_N) * ROWS_PER_BLOCK;
  const int L = lengths[n];
  if (tbase >= L) return;  // whole block past this sequence's length: skip all reads

  const int lane = threadIdx.x & 63;
  const int wid = threadIdx.x >> 6;  // 0..3

  // Preload this lane's w fragment (32 floats = 8 float4) into registers.
  const float4* __restrict__ w4 = reinterpret_cast<const float4*>(w);
  float4 wreg[8];
#pragma unroll
  for (int j = 0; j < 8; ++j) wreg[j] = w4[lane + 64 * j];

#pragma unroll
  for (int i = 0; i < 4; ++i) {
    const int t = tbase + wid * 4 + i;  // wave handles 4 consecutive rows
    if (t >= L) continue;
    const float4* __restrict__ xrow =
        reinterpret_cast<const float4*>(x + ((size_t)n * T + t) * D);
    float acc = 0.0f;
#pragma unroll
    for (int j = 0; j < 8; ++j) {
      float4 v = xrow[lane + 64 * j];
      acc += v.x * wreg[j].x + v.y * wreg[j].y + v.z * wreg[j].z + v.w * wreg[j].w;
    }
    // wave64 butterfly reduction
#pragma unroll
    for (int off = 32; off >= 1; off >>= 1) acc += __shfl_xor(acc, off, 64);
    if (lane == 0) scores[(size_t)n * T + t] = acc;
  }
}

// Phase 2: per n, for each of R bins [r*L/R, ceil((r+1)L/R)) compute max & min
// of scores, sum them all (sort in the reference is permutation-invariant under
// the final sum), apply sigmoid. One block per n.
__global__ __launch_bounds__(256) void minmax_kernel(
    const float* __restrict__ scores, const int* __restrict__ lengths,
    float* __restrict__ out) {
  const int n = blockIdx.x;
  const int L = lengths[n];
  const float* __restrict__ s = scores + (size_t)n * T;
  const int tid = threadIdx.x;
  const int lane = tid & 63, wid = tid >> 6;
  __shared__ float smax[4], smin[4];
  float total = 0.0f;

  for (int r = 0; r < R; ++r) {
    const int start = (r * L) / R;
    const int end = ((r + 1) * L + R - 1) / R;  // bins are never empty for L>=1
    float vmax = -FLT_MAX, vmin = FLT_MAX;
    for (int t = start + tid; t < end; t += 256) {
      float v = s[t];
      vmax = fmaxf(vmax, v);
      vmin = fminf(vmin, v);
    }
#pragma unroll
    for (int off = 32; off >= 1; off >>= 1) {
      vmax = fmaxf(vmax, __shfl_xor(vmax, off, 64));
      vmin = fminf(vmin, __shfl_xor(vmin, off, 64));
    }
    if (lane == 0) { smax[wid] = vmax; smin[wid] = vmin; }
    __syncthreads();
    if (tid == 0) {
      float bmax = smax[0], bmin = smin[0];
#pragma unroll
      for (int k = 1; k < 4; ++k) {
        bmax = fmaxf(bmax, smax[k]);
        bmin = fminf(bmin, smin[k]);
      }
      total += bmax + bmin;
    }
    __syncthreads();  // smem reuse next bin
  }
  if (tid == 0) out[n] = 1.0f / (1.0f + expf(-total));
}

extern "C" void kernel_launch(void* const* d_in, const int* in_sizes, int n_in,
                              void* d_out, int out_size, void* d_ws, size_t ws_size,
                              hipStream_t stream) {
  const float* x = (const float*)d_in[0];
  const int* lengths = (const int*)d_in[1];
  const float* w = (const float*)d_in[2];
  float* out = (float*)d_out;
  float* scores = (float*)d_ws;  // N*T floats = 512 KB

  score_kernel<<<N * BLOCKS_PER_N, 256, 0, stream>>>(x, lengths, w, scores);
  minmax_kernel<<<N, 256, 0, stream>>>(scores, lengths, out);
}